// Round 1
// baseline (59.854 us; speedup 1.0000x reference)
//
#include <hip/hip_runtime.h>

typedef unsigned int u32;
typedef unsigned short u16;
typedef float f32x16 __attribute__((ext_vector_type(16)));
typedef __bf16 bf16x8 __attribute__((ext_vector_type(8)));

union BF8 { u32 w[4]; bf16x8 v; };

#define DEVI static __device__ __forceinline__

DEVI u32 pk_bf16(float lo, float hi) {
  u32 r;
  asm("v_cvt_pk_bf16_f32 %0, %1, %2" : "=v"(r) : "v"(lo), "v"(hi));
  return r;
}
DEVI u16 bf1(float x) { return (u16)(pk_bf16(x, 0.0f) & 0xffffu); }

// ---- workspace layout ----
// float-element offsets in the f32 header region:
#define WS_XG    0        // 512
#define WS_WQ1   512      // 512  (sq1 folded)
#define WS_WQ2   1024     // 256  (sq2 * SC folded)
#define WS_BQ2   1280     // 16   (bq2 * SC)
#define WS_WK1   1296     // 1024 (sk1 folded)
#define WS_WK2   2320     // 256  (sk2 folded)
#define WS_WV    2576     // 1024 (sv folded)
#define WS_WO    3600     // 512  (so folded)
// byte offsets:
#define WB_WREP  17408    // 27*32*64 bf16 = 110592 B
#define WB_QS    131072   // 8192*16 bf16
#define WB_K     393216   // 8192*16 bf16
#define WB_VT    655360   // 16*8192 bf16
#define WB_XT    917504   // 8192*32 bf16
#define WB_CTXP  1441792  // 8192*32 bf16
#define WB_PL    1966080  // 8*8192 f32
#define WB_PCTX  2228224  // 8*8192*16 f32
#define WB_PY    6422528  // 8*32*8192 f32 (ends 14811136)

// ---------------- K0: avg pool over (h,w) per (c,d) ----------------
__global__ void k_pool(const float* __restrict__ x, float* __restrict__ xg) {
  const int b = blockIdx.x, t = threadIdx.x;   // b = c*16+d, 64 threads
  const float* px = x + (b << 9);
  float s = 0.0f;
#pragma unroll
  for (int i = 0; i < 8; ++i) s += px[t + (i << 6)];
#pragma unroll
  for (int off = 32; off > 0; off >>= 1) s += __shfl_down(s, off, 64);
  if (t == 0) xg[b] = s * (1.0f / 512.0f);
}

// ---------------- K0b: fold BN into weights, repack conv weights ----------------
__global__ void k_repack(
    const float* __restrict__ wq1, const float* __restrict__ sq1,
    const float* __restrict__ wq2, const float* __restrict__ sq2,
    const float* __restrict__ bq2,
    const float* __restrict__ wk1, const float* __restrict__ sk1,
    const float* __restrict__ wk2, const float* __restrict__ sk2,
    const float* __restrict__ wv,  const float* __restrict__ sv,
    const float* __restrict__ wo,  const float* __restrict__ so,
    const float* __restrict__ wbot, const float* __restrict__ sbot,
    float* __restrict__ wsf, u16* __restrict__ wrep) {
  const int idx = blockIdx.x * 256 + threadIdx.x;
  const float SC = 0.36067376022224085f;  // CT^-0.5 * log2(e)
  if (idx < 55296) {
    const int tap = idx >> 11, rem = idx & 2047, o = rem >> 6, i = rem & 63;
    wrep[idx] = bf1(wbot[(o * 64 + i) * 27 + tap] * sbot[o]);
    return;
  }
  const int j = idx - 55296;
  if (j < 512)       {                       wsf[WS_WQ1 + j]  = wq1[j]  * sq1[j >> 5]; }
  else if (j < 768)  { const int t2 = j - 512;  wsf[WS_WQ2 + t2] = wq2[t2] * sq2[t2 >> 4] * SC; }
  else if (j < 784)  { const int t2 = j - 768;  wsf[WS_BQ2 + t2] = bq2[t2] * SC; }
  else if (j < 1808) { const int t2 = j - 784;  wsf[WS_WK1 + t2] = wk1[t2] * sk1[t2 >> 6]; }
  else if (j < 2064) { const int t2 = j - 1808; wsf[WS_WK2 + t2] = wk2[t2] * sk2[t2 >> 4]; }
  else if (j < 3088) { const int t2 = j - 2064; wsf[WS_WV + t2]  = wv[t2]  * sv[t2 >> 6]; }
  else if (j < 3600) { const int t2 = j - 3088; wsf[WS_WO + t2]  = wo[t2]  * so[t2 >> 4]; }
}

// ---------------- K1: q/k/v projections + x transpose ----------------
// block: 256 threads = 32 n-positions x 8 output-groups (2 outputs each)
__global__ __launch_bounds__(256) void k_qkv(
    const float* __restrict__ x, const float* __restrict__ wsf,
    const float* __restrict__ bq1, const float* __restrict__ bk1,
    const float* __restrict__ bk2, const float* __restrict__ bv,
    u16* __restrict__ qs, u16* __restrict__ kbm,
    u16* __restrict__ vt, u16* __restrict__ xt) {
  __shared__ float H[2][32][17];
  const int tid = threadIdx.x;
  const int nl = tid & 31, g = tid >> 5;
  const int n = (blockIdx.x << 5) + nl;
  const int d = n >> 9;
  const int r0 = 2 * g, r1 = 2 * g + 1;

  float xr[32], xgv[32];
#pragma unroll
  for (int c = 0; c < 32; ++c) xr[c] = x[(c << 13) + n];
#pragma unroll
  for (int c = 0; c < 32; ++c) xgv[c] = wsf[WS_XG + (c << 4) + d];

  const float4* wq1f = (const float4*)(wsf + WS_WQ1);
  const float4* wk1f = (const float4*)(wsf + WS_WK1);
  const float4* wvf  = (const float4*)(wsf + WS_WV);

  float hq0 = bq1[r0], hq1 = bq1[r1];
  float hk0 = bk1[r0], hk1 = bk1[r1];
  float hv0 = bv[r0],  hv1 = bv[r1];

#pragma unroll
  for (int c4 = 0; c4 < 8; ++c4) {
    const float4 wa = wq1f[r0 * 8 + c4], wb = wq1f[r1 * 8 + c4];
    hq0 += wa.x * xr[4*c4+0] + wa.y * xr[4*c4+1] + wa.z * xr[4*c4+2] + wa.w * xr[4*c4+3];
    hq1 += wb.x * xr[4*c4+0] + wb.y * xr[4*c4+1] + wb.z * xr[4*c4+2] + wb.w * xr[4*c4+3];
  }
#pragma unroll
  for (int c4 = 0; c4 < 8; ++c4) {   // key_feats channels 0..31 = xg broadcast
    const float4 wa = wk1f[r0 * 16 + c4], wb = wk1f[r1 * 16 + c4];
    hk0 += wa.x * xgv[4*c4+0] + wa.y * xgv[4*c4+1] + wa.z * xgv[4*c4+2] + wa.w * xgv[4*c4+3];
    hk1 += wb.x * xgv[4*c4+0] + wb.y * xgv[4*c4+1] + wb.z * xgv[4*c4+2] + wb.w * xgv[4*c4+3];
    const float4 va = wvf[r0 * 16 + c4], vb = wvf[r1 * 16 + c4];
    hv0 += va.x * xgv[4*c4+0] + va.y * xgv[4*c4+1] + va.z * xgv[4*c4+2] + va.w * xgv[4*c4+3];
    hv1 += vb.x * xgv[4*c4+0] + vb.y * xgv[4*c4+1] + vb.z * xgv[4*c4+2] + vb.w * xgv[4*c4+3];
  }
#pragma unroll
  for (int c4 = 0; c4 < 8; ++c4) {   // key_feats channels 32..63 = x
    const float4 wa = wk1f[r0 * 16 + 8 + c4], wb = wk1f[r1 * 16 + 8 + c4];
    hk0 += wa.x * xr[4*c4+0] + wa.y * xr[4*c4+1] + wa.z * xr[4*c4+2] + wa.w * xr[4*c4+3];
    hk1 += wb.x * xr[4*c4+0] + wb.y * xr[4*c4+1] + wb.z * xr[4*c4+2] + wb.w * xr[4*c4+3];
    const float4 va = wvf[r0 * 16 + 8 + c4], vb = wvf[r1 * 16 + 8 + c4];
    hv0 += va.x * xr[4*c4+0] + va.y * xr[4*c4+1] + va.z * xr[4*c4+2] + va.w * xr[4*c4+3];
    hv1 += vb.x * xr[4*c4+0] + vb.y * xr[4*c4+1] + vb.z * xr[4*c4+2] + vb.w * xr[4*c4+3];
  }
  hq0 = fmaxf(hq0, 0.0f); hq1 = fmaxf(hq1, 0.0f);
  hk0 = fmaxf(hk0, 0.0f); hk1 = fmaxf(hk1, 0.0f);
  hv0 = fmaxf(hv0, 0.0f); hv1 = fmaxf(hv1, 0.0f);

  H[0][nl][r0] = hq0; H[0][nl][r1] = hq1;
  H[1][nl][r0] = hk0; H[1][nl][r1] = hk1;
  vt[(r0 << 13) + n] = bf1(hv0);
  vt[(r1 << 13) + n] = bf1(hv1);

  // x transpose (bf16) for the bottleneck conv: channels 4g..4g+3
  const int c0 = g << 2;
  *(u32*)(xt + (n << 5) + c0)     = pk_bf16(x[((c0 + 0) << 13) + n], x[((c0 + 1) << 13) + n]);
  *(u32*)(xt + (n << 5) + c0 + 2) = pk_bf16(x[((c0 + 2) << 13) + n], x[((c0 + 3) << 13) + n]);

  __syncthreads();

  const float* wq2f = wsf + WS_WQ2;
  const float* wk2f = wsf + WS_WK2;
  float q0 = wsf[WS_BQ2 + r0], q1 = wsf[WS_BQ2 + r1];
  float k0 = bk2[r0], k1 = bk2[r1];
#pragma unroll
  for (int j = 0; j < 16; ++j) {
    const float hq = H[0][nl][j], hk = H[1][nl][j];
    q0 += wq2f[r0 * 16 + j] * hq;
    q1 += wq2f[r1 * 16 + j] * hq;
    k0 += wk2f[r0 * 16 + j] * hk;
    k1 += wk2f[r1 * 16 + j] * hk;
  }
  q0 = fmaxf(q0, 0.0f); q1 = fmaxf(q1, 0.0f);
  k0 = fmaxf(k0, 0.0f); k1 = fmaxf(k1, 0.0f);
  *(u32*)(qs  + (n << 4) + r0) = pk_bf16(q0, q1);   // q pre-scaled (folded)
  *(u32*)(kbm + (n << 4) + r0) = pk_bf16(k0, k1);
}

// ---------------- K2: flash attention partials (no-max softmax in exp2 domain) ----------------
// wave = (q-block of 32, key-partition of 1024); 2048 waves
__global__ __launch_bounds__(256) void k_attn(
    const u16* __restrict__ qs, const u16* __restrict__ kbm,
    const u16* __restrict__ vt,
    float* __restrict__ pctx, float* __restrict__ pl) {
  const int wid = (blockIdx.x << 2) + (threadIdx.x >> 6);
  const int lane = threadIdx.x & 63;
  const int l31 = lane & 31, h = lane >> 5;
  const bool lo = (h == 0);
  const int p = wid & 7;
  const int qb = (wid >> 3) << 5;

  const bf16x8 qf = *(const bf16x8*)(qs + ((qb + l31) << 4) + (h << 3));
  f32x16 acc; f32x16 z;
#pragma unroll
  for (int i = 0; i < 16; ++i) { acc[i] = 0.0f; z[i] = 0.0f; }
  float lpart = 0.0f;

  const int kb0 = p << 10;
  for (int t = 0; t < 32; ++t) {
    const int kb = kb0 + (t << 5);
    const bf16x8 kf = *(const bf16x8*)(kbm + ((kb + l31) << 4) + (h << 3));
    // S^T tile: D[key][q] = K * Q^T  (K dim = CT = 16 exactly)
    f32x16 st = __builtin_amdgcn_mfma_f32_32x32x16_bf16(kf, qf, z, 0, 0, 0);
    float pe[16];
#pragma unroll
    for (int r = 0; r < 16; ++r) {
      pe[r] = __builtin_amdgcn_exp2f(st[r]);
      lpart += pe[r];
    }
    // pack P to bf16 and exchange half-wave key-halves to form the PV A-fragment
    const u32 a0 = pk_bf16(pe[0],  pe[1]),  a1 = pk_bf16(pe[2],  pe[3]);
    const u32 a2 = pk_bf16(pe[4],  pe[5]),  a3 = pk_bf16(pe[6],  pe[7]);
    const u32 b0 = pk_bf16(pe[8],  pe[9]),  b1 = pk_bf16(pe[10], pe[11]);
    const u32 b2 = pk_bf16(pe[12], pe[13]), b3 = pk_bf16(pe[14], pe[15]);
    const u32 sa0 = (u32)__shfl_xor((int)a0, 32), sa1 = (u32)__shfl_xor((int)a1, 32);
    const u32 sa2 = (u32)__shfl_xor((int)a2, 32), sa3 = (u32)__shfl_xor((int)a3, 32);
    const u32 sb0 = (u32)__shfl_xor((int)b0, 32), sb1 = (u32)__shfl_xor((int)b1, 32);
    const u32 sb2 = (u32)__shfl_xor((int)b2, 32), sb3 = (u32)__shfl_xor((int)b3, 32);
    BF8 A1, A2;
    A1.w[0] = lo ? a0 : sa2;  A1.w[1] = lo ? a1 : sa3;
    A1.w[2] = lo ? sa0 : a2;  A1.w[3] = lo ? sa1 : a3;
    A2.w[0] = lo ? b0 : sb2;  A2.w[1] = lo ? b1 : sb3;
    A2.w[2] = lo ? sb0 : b2;  A2.w[3] = lo ? sb1 : b3;

    BF8 V1, V2;
    V1.w[0] = V1.w[1] = V1.w[2] = V1.w[3] = 0u;
    V2.w[0] = V2.w[1] = V2.w[2] = V2.w[3] = 0u;
    if (l31 < 16) {
      const u16* vp = vt + (l31 << 13) + kb;
      V1.v = *(const bf16x8*)(vp + (h << 3));
      V2.v = *(const bf16x8*)(vp + 16 + (h << 3));
    }
    acc = __builtin_amdgcn_mfma_f32_32x32x16_bf16(A1.v, V1.v, acc, 0, 0, 0);
    acc = __builtin_amdgcn_mfma_f32_32x32x16_bf16(A2.v, V2.v, acc, 0, 0, 0);
  }
  lpart += __shfl_xor(lpart, 32);
  if (lane < 32) pl[(p << 13) + qb + l31] = lpart;
  if (l31 < 16) {
#pragma unroll
    for (int r = 0; r < 16; ++r) {
      const int row = (r & 3) + ((r >> 2) << 3) + (h << 2);  // q offset
      pctx[(((p << 13) + qb + row) << 4) + l31] = acc[r];
    }
  }
}

// ---------------- K3: combine partials, normalize, fused out-projection ----------------
__global__ __launch_bounds__(256) void k_reduce(
    const float* __restrict__ pctx, const float* __restrict__ pl,
    const float* __restrict__ wsf, const float* __restrict__ bo,
    u16* __restrict__ ctxp) {
  __shared__ float C[16][17];
  const int tid = threadIdx.x;
  const int ctn = tid & 15, nl = tid >> 4;
  const int n = (blockIdx.x << 4) + nl;
  float s = 0.0f, l = 0.0f;
#pragma unroll
  for (int p = 0; p < 8; ++p) {
    s += pctx[(((p << 13) + n) << 4) + ctn];
    l += pl[(p << 13) + n];
  }
  C[nl][ctn] = s / l;
  __syncthreads();
  const float* wof = wsf + WS_WO;
  const int o0 = 2 * ctn, o1 = o0 + 1;
  float y0 = bo[o0], y1 = bo[o1];
#pragma unroll
  for (int j = 0; j < 16; ++j) {
    const float cv = C[nl][j];
    y0 += wof[o0 * 16 + j] * cv;
    y1 += wof[o1 * 16 + j] * cv;
  }
  y0 = fmaxf(y0, 0.0f); y1 = fmaxf(y1, 0.0f);
  *(u32*)(ctxp + (n << 5) + o0) = pk_bf16(y0, y1);
}

// ---------------- K4: 3x3x3 conv as 27 shifted MFMA GEMMs, 8-way tap-split ----------------
__global__ __launch_bounds__(256) void k_conv(
    const u16* __restrict__ xt, const u16* __restrict__ ctxp,
    const u16* __restrict__ wrep, float* __restrict__ py) {
  const int wid = (blockIdx.x << 2) + (threadIdx.x >> 6);
  const int lane = threadIdx.x & 63;
  const int l31 = lane & 31, h = lane >> 5;
  const int part = wid & 7, nb = wid >> 3;
  const int n0 = nb << 5;
  const int dz = n0 >> 9, hy = (n0 >> 5) & 15;
  const int tlo = (part * 27) >> 3, thi = ((part + 1) * 27) >> 3;
  f32x16 acc;
#pragma unroll
  for (int i = 0; i < 16; ++i) acc[i] = 0.0f;

  for (int tap = tlo; tap < thi; ++tap) {
    const int dd = tap / 9 - 1;
    const int dh = (tap / 3) % 3 - 1;
    const int dw = tap % 3 - 1;
    if ((unsigned)(dz + dd) >= 16u) continue;
    if ((unsigned)(hy + dh) >= 16u) continue;
    const bool okw = (unsigned)(l31 + dw) < 32u;
    const int nn = n0 + dd * 512 + dh * 32 + dw + l31;
    const u16* wp = wrep + ((tap * 32 + l31) << 6) + (h << 3);
#pragma unroll
    for (int c = 0; c < 4; ++c) {
      const bf16x8 af = *(const bf16x8*)(wp + (c << 4));
      BF8 B_;
      B_.w[0] = B_.w[1] = B_.w[2] = B_.w[3] = 0u;
      if (okw) {
        if (c < 2) B_.v = *(const bf16x8*)(xt + (nn << 5) + (c << 4) + (h << 3));
        else       B_.v = *(const bf16x8*)(ctxp + (nn << 5) + ((c - 2) << 4) + (h << 3));
      }
      acc = __builtin_amdgcn_mfma_f32_32x32x16_bf16(af, B_.v, acc, 0, 0, 0);
    }
  }
#pragma unroll
  for (int r = 0; r < 16; ++r) {
    const int row = (r & 3) + ((r >> 2) << 3) + (h << 2);  // output channel
    py[((part << 5) + row) * 8192 + n0 + l31] = acc[r];
  }
}

// ---------------- K5: sum conv partials + bias + LeakyReLU ----------------
__global__ __launch_bounds__(256) void k_final(
    const float* __restrict__ py, const float* __restrict__ bbot,
    float* __restrict__ out) {
  const int idx = blockIdx.x * 256 + threadIdx.x;
  float s = bbot[idx >> 13];
#pragma unroll
  for (int p = 0; p < 8; ++p) s += py[(p << 18) + idx];
  out[idx] = s > 0.0f ? s : 0.1f * s;
}

extern "C" void kernel_launch(void* const* d_in, const int* in_sizes, int n_in,
                              void* d_out, int out_size, void* d_ws, size_t ws_size,
                              hipStream_t stream) {
  const float* x    = (const float*)d_in[0];
  const float* wq1  = (const float*)d_in[1];
  const float* sq1  = (const float*)d_in[2];
  const float* bq1  = (const float*)d_in[3];
  const float* wq2  = (const float*)d_in[4];
  const float* sq2  = (const float*)d_in[5];
  const float* bq2  = (const float*)d_in[6];
  const float* wk1  = (const float*)d_in[7];
  const float* sk1  = (const float*)d_in[8];
  const float* bk1  = (const float*)d_in[9];
  const float* wk2  = (const float*)d_in[10];
  const float* sk2  = (const float*)d_in[11];
  const float* bk2  = (const float*)d_in[12];
  const float* wv   = (const float*)d_in[13];
  const float* sv   = (const float*)d_in[14];
  const float* bv   = (const float*)d_in[15];
  const float* wo   = (const float*)d_in[16];
  const float* so   = (const float*)d_in[17];
  const float* bo   = (const float*)d_in[18];
  const float* wbot = (const float*)d_in[19];
  const float* sbot = (const float*)d_in[20];
  const float* bbot = (const float*)d_in[21];
  (void)in_sizes; (void)n_in; (void)out_size; (void)ws_size; (void)sbot;

  float* wsf = (float*)d_ws;
  char*  wsb = (char*)d_ws;
  u16* wrep = (u16*)(wsb + WB_WREP);
  u16* qs   = (u16*)(wsb + WB_QS);
  u16* kbm  = (u16*)(wsb + WB_K);
  u16* vt   = (u16*)(wsb + WB_VT);
  u16* xt   = (u16*)(wsb + WB_XT);
  u16* ctxp = (u16*)(wsb + WB_CTXP);
  float* pl   = (float*)(wsb + WB_PL);
  float* pctx = (float*)(wsb + WB_PCTX);
  float* py   = (float*)(wsb + WB_PY);
  float* out  = (float*)d_out;

  k_pool<<<512, 64, 0, stream>>>(x, wsf + WS_XG);
  k_repack<<<231, 256, 0, stream>>>(wq1, sq1, wq2, sq2, bq2, wk1, sk1,
                                    wk2, sk2, wv, sv, wo, so, wbot, sbot,
                                    wsf, wrep);
  k_qkv<<<256, 256, 0, stream>>>(x, wsf, bq1, bk1, bk2, bv, qs, kbm, vt, xt);
  k_attn<<<512, 256, 0, stream>>>(qs, kbm, vt, pctx, pl);
  k_reduce<<<512, 256, 0, stream>>>(pctx, pl, wsf, bo, ctxp);
  k_conv<<<512, 256, 0, stream>>>(xt, ctxp, wrep, py);
  k_final<<<1024, 256, 0, stream>>>(py, bbot, out);
}